// Round 10
// baseline (649.002 us; speedup 1.0000x reference)
//
#include <hip/hip_runtime.h>
#include <hip/hip_bf16.h>

#define HID   2048
#define NTOK  4096
#define NEXP  24
#define SHCOL 4096     // shared intermediate columns (2 x 2048)
#define TOPK  6
#define NSLOT (NTOK * TOPK)   // 24576

typedef __bf16 bf16_t;
typedef __bf16 bf16x8 __attribute__((ext_vector_type(8)));
typedef __bf16 bf16x4 __attribute__((ext_vector_type(4)));
typedef float  f32x4  __attribute__((ext_vector_type(4)));

// ---------------- async global->LDS 16B ----------------
__device__ __forceinline__ void async_copy16(const bf16_t* g, bf16_t* l) {
  __builtin_amdgcn_global_load_lds(
      (const __attribute__((address_space(1))) unsigned int*)g,
      (__attribute__((address_space(3))) unsigned int*)l,
      16, 0, 0);
}
template<int N> __device__ __forceinline__ void wait_vm() {
  asm volatile("s_waitcnt vmcnt(%0)" :: "n"(N) : "memory");
}
__device__ __forceinline__ void memfence_sched() { asm volatile("" ::: "memory"); }

// BK=32 tile region (rows x 32 bf16, 64B rows; 4 chunks of 16B per row).
// Physical chunk = cc ^ ((row>>1)&3): 16 consecutive rows span all 8
// bank-groups -> 2-way (free). Staging pre-swizzles the global source.
__device__ __forceinline__ bf16x8 frag32(const bf16_t* region, int row, int cc) {
  return *(const bf16x8*)(region + row * 32 + ((cc ^ ((row >> 1) & 3)) << 3));
}

// ---------------- fused prep: cast x + 6 transpose jobs ----------------
__device__ __forceinline__ void tcast_tile(
    const float* __restrict__ src, bf16_t* __restrict__ dst,
    int C, long dstStride, int c0, int r0, int tid) {
  __shared__ float t[64][68];
  {
    const int tr = tid >> 4, tc = tid & 15;
#pragma unroll
    for (int p = 0; p < 4; ++p) {
      const int r = p * 16 + tr;
      const float4 v = *(const float4*)(src + (long)(r0 + r) * C + c0 + tc * 4);
      *(float4*)&t[r][tc * 4] = v;
    }
  }
  __syncthreads();
  {
    const int l8 = tid & 7, rb = l8 * 8;
#pragma unroll
    for (int p = 0; p < 2; ++p) {
      const int c = p * 32 + (tid >> 3);
      bf16x8 o;
#pragma unroll
      for (int s = 0; s < 8; ++s) o[s] = (bf16_t)t[rb + s][c];
      *(bf16x8*)(dst + (long)(c0 + c) * dstStride + r0 + rb) = o;
    }
  }
}

__global__ __launch_bounds__(256) void prep(
    const float* __restrict__ x, bf16_t* __restrict__ xb,
    const float* __restrict__ sw1, const float* __restrict__ rw1,
    const float* __restrict__ sw3, const float* __restrict__ rw3,
    const float* __restrict__ sw2, const float* __restrict__ rw2,
    bf16_t* __restrict__ w1t, bf16_t* __restrict__ w3t,
    bf16_t* __restrict__ w2ts, bf16_t* __restrict__ rw2t) {
  int bid = blockIdx.x;
  if (bid < 8192) {                      // cast x -> bf16
    int i = bid * 256 + threadIdx.x;
    float4 v = ((const float4*)x)[i];
    bf16x4 o = { (bf16_t)v.x, (bf16_t)v.y, (bf16_t)v.z, (bf16_t)v.w };
    ((bf16x4*)xb)[i] = o;
    return;
  }
  bid -= 8192;
  const float* src; bf16_t* dst; int C; long dstStride, seS, deS; int BX, nPer;
  if (bid < 2048)       { src=sw1; dst=w1t;                  C=2048; dstStride=2048; seS=2048L*2048; deS=2048L*2048; BX=32; nPer=1024; }
  else if (bid < 8192)  { bid-=2048;  src=rw1; dst=w1t+(long)SHCOL*HID; C=512;  dstStride=2048; seS=2048L*512;  deS=512L*2048;  BX=8;  nPer=256; }
  else if (bid < 10240) { bid-=8192;  src=sw3; dst=w3t;                 C=2048; dstStride=2048; seS=2048L*2048; deS=2048L*2048; BX=32; nPer=1024; }
  else if (bid < 16384) { bid-=10240; src=rw3; dst=w3t+(long)SHCOL*HID; C=512;  dstStride=2048; seS=2048L*512;  deS=512L*2048;  BX=8;  nPer=256; }
  else if (bid < 18432) { bid-=16384; src=sw2; dst=w2ts;                C=2048; dstStride=4096; seS=2048L*2048; deS=2048;       BX=32; nPer=1024; }
  else                  { bid-=18432; src=rw2; dst=rw2t;                C=2048; dstStride=512;  seS=512L*2048;  deS=2048L*512;  BX=32; nPer=256; }
  const int e  = bid / nPer;
  const int rem = bid - e * nPer;
  const int by = rem / BX;
  const int bx = rem - by * BX;
  tcast_tile(src + (long)e * seS, dst + (long)e * deS, C, dstStride,
             bx * 64, by * 64, threadIdx.x);
}

// gate: sigmoid(x @ gate_w^T), top-6 -> (idx, normalized weight) per token
__global__ void gate_topk(const float* __restrict__ x, const float* __restrict__ gw,
                          int* __restrict__ tk_idx, float* __restrict__ tk_w,
                          float* __restrict__ aux) {
  int lane = threadIdx.x & 63;
  int wave = threadIdx.x >> 6;
  int token = blockIdx.x * 4 + wave;
  const float* xr = x + (long)token * HID;
  float xv[32];
#pragma unroll
  for (int i = 0; i < 32; ++i) xv[i] = xr[lane + i * 64];
  float sc[NEXP];
#pragma unroll
  for (int e = 0; e < NEXP; ++e) {
    const float* g = gw + (long)e * HID;
    float s = 0.f;
#pragma unroll
    for (int i = 0; i < 32; ++i) s += xv[i] * g[lane + i * 64];
#pragma unroll
    for (int off = 32; off > 0; off >>= 1) s += __shfl_down(s, off);
    sc[e] = s;
  }
  if (lane == 0) {
    float sg[NEXP];
#pragma unroll
    for (int e = 0; e < NEXP; ++e) sg[e] = 1.0f / (1.0f + expf(-sc[e]));
    unsigned taken = 0;
    int   sel[TOPK];
    float sw[TOPK];
    float sum = 0.f;
    for (int k = 0; k < TOPK; ++k) {
      float best = -1.f; int bi = 0;
#pragma unroll
      for (int e = 0; e < NEXP; ++e) {
        bool avail = !(taken & (1u << e));
        if (avail && sg[e] > best) { best = sg[e]; bi = e; }
      }
      taken |= (1u << bi);
      sel[k] = bi; sw[k] = best; sum += best;
    }
    float inv = 1.0f / (sum + 1e-9f);
#pragma unroll
    for (int k = 0; k < TOPK; ++k) {
      tk_idx[token * TOPK + k] = sel[k];
      tk_w[token * TOPK + k]   = sw[k] * inv;
    }
  }
  if (blockIdx.x == 0 && threadIdx.x == 0) *aux = 0.0f;
}

// dispatch: per-expert token lists + tile tables (256-row for up, 128 for down)
// meta: [0]=up_nt [1]=down_nt [8+e]=cnt[e] [32+e]=off[e]
__global__ void dispatch(const int* __restrict__ tk_idx, const float* __restrict__ tk_w,
                         int* __restrict__ perm, float* __restrict__ wslot,
                         int* __restrict__ slot_of, int* __restrict__ meta,
                         int* __restrict__ uptab, int* __restrict__ dntab) {
  __shared__ int cnt[NEXP], cnt2[NEXP], off[NEXP + 1];
  int tid = threadIdx.x;
  if (tid < NEXP) { cnt[tid] = 0; cnt2[tid] = 0; }
  __syncthreads();
  for (int i = tid; i < NSLOT; i += 1024) atomicAdd(&cnt[tk_idx[i]], 1);
  __syncthreads();
  if (tid == 0) {
    int o = 0, un = 0, dn = 0;
    for (int e = 0; e < NEXP; ++e) {
      off[e] = o;
      int c = cnt[e];
      for (int r0 = 0; r0 < c; r0 += 256) uptab[un++] = (e << 16) | r0;
      for (int r0 = 0; r0 < c; r0 += 128) dntab[dn++] = (e << 16) | r0;
      o += c;
    }
    off[NEXP] = o;
    meta[0] = un; meta[1] = dn;
    for (int e = 0; e < NEXP; ++e) { meta[8 + e] = cnt[e]; meta[32 + e] = off[e]; }
  }
  __syncthreads();
  for (int i = tid; i < NSLOT; i += 1024) {
    int e = tk_idx[i];
    int loc = atomicAdd(&cnt2[e], 1);
    int slot = off[e] + loc;
    perm[slot] = i / TOPK;
    wslot[slot] = tk_w[i];
    slot_of[i] = slot;
  }
}

// ---------------- merged up GEMM (256x128 dual, 4-slot ring, depth-3) -----
// compute cluster = r3's verified single-phase form; staging after barrier.
__global__ __launch_bounds__(512, 2) void gemm_up(
    const bf16_t* __restrict__ xb, const bf16_t* __restrict__ w1t,
    const bf16_t* __restrict__ w3t, bf16_t* __restrict__ hsh,
    bf16_t* __restrict__ hr, const int* __restrict__ perm,
    const float* __restrict__ wslot, const int* __restrict__ meta,
    const int* __restrict__ uptab) {
  __shared__ bf16_t lds[4 * 16384];   // slot: A 8192 | B1 4096 | B3 4096 elems
  const int bid = blockIdx.x;
  const int tid  = threadIdx.x;
  const int lane = tid & 63;
  const int wave = tid >> 6;
  const int wm = wave >> 2;
  const int wc = wave & 3;
  const bool role_sh = bid < 512;
  int m0 = 0, j0 = 0, jc = 0, M = 256, bslot = 0;
  const bf16_t *b1G, *b3G;
  if (role_sh) {
    m0 = (bid >> 5) * 256; j0 = (bid & 31) * 128;
    b1G = w1t + (long)j0 * HID;
    b3G = w3t + (long)j0 * HID;
  } else {
    int t = bid - 512;
    int rt = t >> 2; jc = t & 3;
    if (rt >= meta[0]) return;
    int pk = uptab[rt];
    int e = pk >> 16, row0 = pk & 0xffff;
    bslot = meta[32 + e] + row0;
    M = min(256, meta[8 + e] - row0);
    int col = SHCOL + e * 512 + jc * 128;
    b1G = w1t + (long)col * HID;
    b3G = w3t + (long)col * HID;
  }
  const bf16_t* gsrc[4];
  int loff[4];
#pragma unroll
  for (int it = 0; it < 4; ++it) {
    int idx = it * 512 + tid;
    if (idx < 1024) {                     // A region: 256 rows x 4 chunks
      int r = idx >> 2, c = idx & 3;
      long rowbase;
      if (role_sh) rowbase = (long)(m0 + r) * HID;
      else         rowbase = (long)perm[bslot + ((r < M) ? r : 0)] * HID;
      gsrc[it] = xb + rowbase + ((c ^ ((r >> 1) & 3)) << 3);
      loff[it] = idx << 3;
    } else if (idx < 1536) {
      int i2 = idx - 1024; int r = i2 >> 2, c = i2 & 3;
      gsrc[it] = b1G + (long)r * HID + ((c ^ ((r >> 1) & 3)) << 3);
      loff[it] = 8192 + (i2 << 3);
    } else {
      int i2 = idx - 1536; int r = i2 >> 2, c = i2 & 3;
      gsrc[it] = b3G + (long)r * HID + ((c ^ ((r >> 1) & 3)) << 3);
      loff[it] = 12288 + (i2 << 3);
    }
  }
  auto STAGE = [&](int t) {
    bf16_t* sb = lds + (t & 3) * 16384;
#pragma unroll
    for (int it = 0; it < 4; ++it)        // 4 loads/thread per tile
      async_copy16(gsrc[it] + t * 32, sb + loff[it]);
  };

  f32x4 acc1[8][2] = {};
  f32x4 acc3[8][2] = {};
  const int NT = HID / 32;              // 64
  const int rA = wm * 128 + (lane & 15);
  const int rB = wc * 32 + (lane & 15);
  const int cc = lane >> 4;             // 16B chunk 0..3 within 32-elem row
  STAGE(0); STAGE(1); STAGE(2);
  for (int t = 0; t < NT; ++t) {
    // outstanding at this point: tiles t, t+1, t+2 (4 loads each).
    if (t + 2 < NT)      wait_vm<8>();  // drain tile t; t+1,t+2 in flight
    else if (t + 1 < NT) wait_vm<4>();
    else                 wait_vm<0>();
    __builtin_amdgcn_s_barrier();       // all waves retired step t-1 reads
    memfence_sched();
    if (t + 3 < NT) STAGE(t + 3);       // writes slot (t-1)&3: safe after bar
    const bf16_t* sb = lds + (t & 3) * 16384;
    bf16x8 a[8], b1[2], b3[2];
#pragma unroll
    for (int fm = 0; fm < 8; ++fm) a[fm] = frag32(sb, rA + fm * 16, cc);
#pragma unroll
    for (int fn = 0; fn < 2; ++fn) {
      b1[fn] = frag32(sb + 8192,  rB + fn * 16, cc);
      b3[fn] = frag32(sb + 12288, rB + fn * 16, cc);
    }
    __builtin_amdgcn_s_setprio(1);
#pragma unroll
    for (int fn = 0; fn < 2; ++fn)
#pragma unroll
      for (int fm = 0; fm < 8; ++fm) {
        acc1[fm][fn] = __builtin_amdgcn_mfma_f32_16x16x32_bf16(a[fm], b1[fn], acc1[fm][fn], 0, 0, 0);
        acc3[fm][fn] = __builtin_amdgcn_mfma_f32_16x16x32_bf16(a[fm], b3[fn], acc3[fm][fn], 0, 0, 0);
      }
    __builtin_amdgcn_s_setprio(0);
    memfence_sched();
  }
  const int mloc_base = wm * 128 + ((lane >> 4) << 2);
  const int cloc = wc * 32 + (lane & 15);
#pragma unroll
  for (int fm = 0; fm < 8; ++fm) {
#pragma unroll
    for (int jj = 0; jj < 4; ++jj) {
      const int mloc = mloc_base + fm * 16 + jj;
      if (role_sh) {
        bf16_t* dst = hsh + (long)(m0 + mloc) * SHCOL + j0 + cloc;
#pragma unroll
        for (int fn = 0; fn < 2; ++fn) {
          const float u1 = acc1[fm][fn][jj];
          const float u3 = acc3[fm][fn][jj];
          dst[fn * 16] = (bf16_t)((u1 / (1.0f + __expf(-u1))) * u3);
        }
      } else if (mloc < M) {
        const int slot = bslot + mloc;
        const float w = wslot[slot];
        bf16_t* dst = hr + (long)slot * 512 + jc * 128 + cloc;
#pragma unroll
        for (int fn = 0; fn < 2; ++fn) {
          const float u1 = acc1[fm][fn][jj];
          const float u3 = acc3[fm][fn][jj];
          dst[fn * 16] = (bf16_t)((u1 / (1.0f + __expf(-u1))) * u3 * w);
        }
      }
    }
  }
}

// ---------------- merged down GEMM (128x256, 3-slot ring, depth-2) --------
__global__ __launch_bounds__(512, 2) void gemm_down(
    const bf16_t* __restrict__ hsh, const bf16_t* __restrict__ w2ts,
    const bf16_t* __restrict__ hr, const bf16_t* __restrict__ rw2t,
    float* __restrict__ sout, bf16_t* __restrict__ y,
    const int* __restrict__ meta, const int* __restrict__ dntab) {
  __shared__ bf16_t lds[3 * 12288];   // slot: A 4096 | B 8192 elems
  const int bid = blockIdx.x;
  const int tid  = threadIdx.x;
  const int lane = tid & 63;
  const int wave = tid >> 6;
  const int wm = wave >> 2;
  const int wc = wave & 3;
  const bool role_sh = bid < 256;
  int m0 = 0, n0, M = 128, bslot = 0, NT;
  const bf16_t *aG, *bG;
  long lda, ldb;
  if (role_sh) {
    m0 = (bid >> 3) * 128; n0 = (bid & 7) * 256;
    aG = hsh + (long)m0 * SHCOL; lda = SHCOL;
    bG = w2ts + (long)n0 * SHCOL; ldb = SHCOL;
    NT = SHCOL / 32;                  // 128
  } else {
    int t = bid - 256;
    int rt = t >> 3; n0 = (t & 7) * 256;
    if (rt >= meta[1]) return;
    int pk = dntab[rt];
    int e = pk >> 16, row0 = pk & 0xffff;
    bslot = meta[32 + e] + row0;
    M = min(128, meta[8 + e] - row0);
    aG = hr + (long)bslot * 512; lda = 512;
    bG = rw2t + (long)e * (2048L * 512) + (long)n0 * 512; ldb = 512;
    NT = 512 / 32;                    // 16
  }
  const bf16_t* gsrc[3];
  int loff[3];
#pragma unroll
  for (int it = 0; it < 3; ++it) {
    int idx = it * 512 + tid;
    if (idx < 512) {                      // A: 128 rows x 4 chunks
      int r = idx >> 2, c = idx & 3;
      gsrc[it] = aG + (long)r * lda + ((c ^ ((r >> 1) & 3)) << 3);
      loff[it] = idx << 3;
    } else {                              // B: 256 rows x 4 chunks
      int i2 = idx - 512; int r = i2 >> 2, c = i2 & 3;
      gsrc[it] = bG + (long)r * ldb + ((c ^ ((r >> 1) & 3)) << 3);
      loff[it] = 4096 + (i2 << 3);
    }
  }
  auto STAGE = [&](int t) {
    bf16_t* sb = lds + (t % 3) * 12288;
#pragma unroll
    for (int it = 0; it < 3; ++it)
      async_copy16(gsrc[it] + t * 32, sb + loff[it]);
  };

  f32x4 acc[4][4] = {};
  const int rA = wm * 64 + (lane & 15);
  const int rB = wc * 64 + (lane & 15);
  const int cc = lane >> 4;
  STAGE(0); STAGE(1);
  for (int t = 0; t < NT; ++t) {
    if (t + 1 < NT) wait_vm<3>();     // drain S(t); S(t+1) stays in flight
    else            wait_vm<0>();
    __builtin_amdgcn_s_barrier();     // all waves done compute(t-1)
    memfence_sched();
    if (t + 2 < NT) STAGE(t + 2);     // slot (t+2)%3 = (t-1)%3, safe after bar
    const bf16_t* sb = lds + (t % 3) * 12288;
    bf16x8 a[4], b[4];
#pragma unroll
    for (int fm = 0; fm < 4; ++fm) a[fm] = frag32(sb, rA + fm * 16, cc);
#pragma unroll
    for (int fn = 0; fn < 4; ++fn) b[fn] = frag32(sb + 4096, rB + fn * 16, cc);
    __builtin_amdgcn_s_setprio(1);
#pragma unroll
    for (int fn = 0; fn < 4; ++fn)
#pragma unroll
      for (int fm = 0; fm < 4; ++fm)
        acc[fm][fn] = __builtin_amdgcn_mfma_f32_16x16x32_bf16(a[fm], b[fn], acc[fm][fn], 0, 0, 0);
    __builtin_amdgcn_s_setprio(0);
    memfence_sched();
  }
  const int mloc_base = wm * 64 + ((lane >> 4) << 2);
  const int cbase = n0 + wc * 64 + (lane & 15);
#pragma unroll
  for (int fm = 0; fm < 4; ++fm)
#pragma unroll
    for (int jj = 0; jj < 4; ++jj) {
      const int mloc = mloc_base + fm * 16 + jj;
      if (role_sh) {
#pragma unroll
        for (int fn = 0; fn < 4; ++fn)
          sout[(long)(m0 + mloc) * HID + cbase + fn * 16] = acc[fm][fn][jj];
      } else if (mloc < M) {
#pragma unroll
        for (int fn = 0; fn < 4; ++fn)
          y[(long)(bslot + mloc) * HID + cbase + fn * 16] = (bf16_t)acc[fm][fn][jj];
      }
    }
}

// combine: out[n] = s_out[n] + sum_k y[slot_of[n][k]]
__global__ void combine(const float* __restrict__ sout, const bf16_t* __restrict__ y,
                        const int* __restrict__ slot_of, float* __restrict__ out) {
  const int n = blockIdx.x;
  const int c0 = threadIdx.x * 8;
  float acc[8];
  const float4* sp = (const float4*)(sout + (long)n * HID + c0);
  float4 s0 = sp[0], s1 = sp[1];
  acc[0]=s0.x; acc[1]=s0.y; acc[2]=s0.z; acc[3]=s0.w;
  acc[4]=s1.x; acc[5]=s1.y; acc[6]=s1.z; acc[7]=s1.w;
#pragma unroll
  for (int k = 0; k < TOPK; ++k) {
    int slot = slot_of[n * TOPK + k];
    bf16x8 v = *(const bf16x8*)(y + (long)slot * HID + c0);
#pragma unroll
    for (int i = 0; i < 8; ++i) acc[i] += (float)v[i];
  }
  float4* op = (float4*)(out + (long)n * HID + c0);
  op[0] = make_float4(acc[0], acc[1], acc[2], acc[3]);
  op[1] = make_float4(acc[4], acc[5], acc[6], acc[7]);
}

__global__ void fill_sentinel(float* out, int n) {
  for (int i = blockIdx.x * 256 + threadIdx.x; i < n; i += gridDim.x * 256)
    out[i] = 12345.0f;
}

// ---------------- launch ----------------
extern "C" void kernel_launch(void* const* d_in, const int* in_sizes, int n_in,
                              void* d_out, int out_size, void* d_ws, size_t ws_size,
                              hipStream_t stream) {
  (void)in_sizes; (void)n_in;
  const float* x   = (const float*)d_in[0];
  const float* gw  = (const float*)d_in[1];
  const float* sw1 = (const float*)d_in[2];
  const float* sw2 = (const float*)d_in[3];   // dict order: w1, w2, w3
  const float* sw3 = (const float*)d_in[4];
  const float* rw1 = (const float*)d_in[5];
  const float* rw2 = (const float*)d_in[6];
  const float* rw3 = (const float*)d_in[7];
  float* out = (float*)d_out;

  const size_t OFF_XB    = 0;
  const size_t OFF_W1T   = 16777216;
  const size_t OFF_W3T   = 83886080;
  const size_t OFF_W2TS  = 150994944;
  const size_t OFF_RW2T  = 167772160;
  const size_t OFF_HSH   = 218103808;
  const size_t OFF_HR    = 251658240;
  const size_t OFF_SOUT  = 277086208;
  const size_t OFF_TKI   = 310640640;
  const size_t OFF_TKW   = 310738944;
  const size_t OFF_PERM  = 310837248;
  const size_t OFF_WSLOT = 310935552;
  const size_t OFF_SLOTOF= 311033856;
  const size_t OFF_META  = 311132160;
  const size_t OFF_UPTAB = 311136256;
  const size_t OFF_DNTAB = 311140352;
  const size_t NEED      = 311148544;
  if (ws_size < NEED) {
    fill_sentinel<<<4096, 256, 0, stream>>>(out, out_size);
    return;
  }
  char* ws = (char*)d_ws;
  bf16_t* xb     = (bf16_t*)(ws + OFF_XB);
  bf16_t* w1t    = (bf16_t*)(ws + OFF_W1T);
  bf16_t* w3t    = (bf16_t*)(ws + OFF_W3T);
  bf16_t* w2ts   = (bf16_t*)(ws + OFF_W2TS);
  bf16_t* rw2t   = (bf16_t*)(ws + OFF_RW2T);
  bf16_t* hsh    = (bf16_t*)(ws + OFF_HSH);
  bf16_t* hr     = (bf16_t*)(ws + OFF_HR);
  float*  sout   = (float*)(ws + OFF_SOUT);
  bf16_t* y      = (bf16_t*)(ws + OFF_W1T);   // overlay (dead after up GEMM)
  int*    tki    = (int*)(ws + OFF_TKI);
  float*  tkw    = (float*)(ws + OFF_TKW);
  int*    perm   = (int*)(ws + OFF_PERM);
  float*  wslot  = (float*)(ws + OFF_WSLOT);
  int*    slotof = (int*)(ws + OFF_SLOTOF);
  int*    meta   = (int*)(ws + OFF_META);
  int*    uptab  = (int*)(ws + OFF_UPTAB);
  int*    dntab  = (int*)(ws + OFF_DNTAB);

  gate_topk<<<1024, 256, 0, stream>>>(x, gw, tki, tkw, out + (size_t)NTOK * HID);
  dispatch<<<1, 1024, 0, stream>>>(tki, tkw, perm, wslot, slotof, meta, uptab, dntab);
  prep<<<32768, 256, 0, stream>>>(x, xb, sw1, rw1, sw3, rw3, sw2, rw2,
                                  w1t, w3t, w2ts, rw2t);

  gemm_up<<<dim3(512 + 480), 512, 0, stream>>>(xb, w1t, w3t, hsh, hr, perm, wslot, meta, uptab);
  gemm_down<<<dim3(256 + 1728), 512, 0, stream>>>(hsh, w2ts, hr, rw2t, sout, y, meta, dntab);
  combine<<<dim3(NTOK), 256, 0, stream>>>(sout, y, slotof, out);
}

// Round 11
// 636.587 us; speedup vs baseline: 1.0195x; 1.0195x over previous
//
#include <hip/hip_runtime.h>
#include <hip/hip_bf16.h>

#define HID   2048
#define NTOK  4096
#define NEXP  24
#define SHCOL 4096     // shared intermediate columns (2 x 2048)
#define TOPK  6
#define NSLOT (NTOK * TOPK)   // 24576

typedef __bf16 bf16_t;
typedef __bf16 bf16x8 __attribute__((ext_vector_type(8)));
typedef __bf16 bf16x4 __attribute__((ext_vector_type(4)));
typedef float  f32x4  __attribute__((ext_vector_type(4)));

// ---------------- async global->LDS 16B ----------------
__device__ __forceinline__ void async_copy16(const bf16_t* g, bf16_t* l) {
  __builtin_amdgcn_global_load_lds(
      (const __attribute__((address_space(1))) unsigned int*)g,
      (__attribute__((address_space(3))) unsigned int*)l,
      16, 0, 0);
}
template<int N> __device__ __forceinline__ void wait_vm() {
  asm volatile("s_waitcnt vmcnt(%0)" :: "n"(N) : "memory");
}
__device__ __forceinline__ void memfence_sched() { asm volatile("" ::: "memory"); }
__device__ __forceinline__ void barp() {           // phase barrier
  memfence_sched(); __builtin_amdgcn_s_barrier(); memfence_sched();
}

// BK=32 region (rows x 32 bf16, 64B rows; 4 chunks). chunk = cc ^ ((row>>1)&3)
__device__ __forceinline__ bf16x8 frag32(const bf16_t* region, int row, int cc) {
  return *(const bf16x8*)(region + row * 32 + ((cc ^ ((row >> 1) & 3)) << 3));
}
// BK=64 region (rows x 64 bf16, 128B rows; 8 chunks). chunk = c8 ^ (row&7):
// 8 consecutive rows span all 8 bank-groups -> 2-way over 16 rows (free).
__device__ __forceinline__ bf16x8 frag64(const bf16_t* region, int row, int c8) {
  return *(const bf16x8*)(region + row * 64 + ((c8 ^ (row & 7)) << 3));
}

// ---------------- fused prep: cast x + 6 transpose jobs ----------------
__device__ __forceinline__ void tcast_tile(
    const float* __restrict__ src, bf16_t* __restrict__ dst,
    int C, long dstStride, int c0, int r0, int tid) {
  __shared__ float t[64][68];
  {
    const int tr = tid >> 4, tc = tid & 15;
#pragma unroll
    for (int p = 0; p < 4; ++p) {
      const int r = p * 16 + tr;
      const float4 v = *(const float4*)(src + (long)(r0 + r) * C + c0 + tc * 4);
      *(float4*)&t[r][tc * 4] = v;
    }
  }
  __syncthreads();
  {
    const int l8 = tid & 7, rb = l8 * 8;
#pragma unroll
    for (int p = 0; p < 2; ++p) {
      const int c = p * 32 + (tid >> 3);
      bf16x8 o;
#pragma unroll
      for (int s = 0; s < 8; ++s) o[s] = (bf16_t)t[rb + s][c];
      *(bf16x8*)(dst + (long)(c0 + c) * dstStride + r0 + rb) = o;
    }
  }
}

__global__ __launch_bounds__(256) void prep(
    const float* __restrict__ x, bf16_t* __restrict__ xb,
    const float* __restrict__ sw1, const float* __restrict__ rw1,
    const float* __restrict__ sw3, const float* __restrict__ rw3,
    const float* __restrict__ sw2, const float* __restrict__ rw2,
    bf16_t* __restrict__ w1t, bf16_t* __restrict__ w3t,
    bf16_t* __restrict__ w2ts, bf16_t* __restrict__ rw2t) {
  int bid = blockIdx.x;
  if (bid < 8192) {                      // cast x -> bf16
    int i = bid * 256 + threadIdx.x;
    float4 v = ((const float4*)x)[i];
    bf16x4 o = { (bf16_t)v.x, (bf16_t)v.y, (bf16_t)v.z, (bf16_t)v.w };
    ((bf16x4*)xb)[i] = o;
    return;
  }
  bid -= 8192;
  const float* src; bf16_t* dst; int C; long dstStride, seS, deS; int BX, nPer;
  if (bid < 2048)       { src=sw1; dst=w1t;                  C=2048; dstStride=2048; seS=2048L*2048; deS=2048L*2048; BX=32; nPer=1024; }
  else if (bid < 8192)  { bid-=2048;  src=rw1; dst=w1t+(long)SHCOL*HID; C=512;  dstStride=2048; seS=2048L*512;  deS=512L*2048;  BX=8;  nPer=256; }
  else if (bid < 10240) { bid-=8192;  src=sw3; dst=w3t;                 C=2048; dstStride=2048; seS=2048L*2048; deS=2048L*2048; BX=32; nPer=1024; }
  else if (bid < 16384) { bid-=10240; src=rw3; dst=w3t+(long)SHCOL*HID; C=512;  dstStride=2048; seS=2048L*512;  deS=512L*2048;  BX=8;  nPer=256; }
  else if (bid < 18432) { bid-=16384; src=sw2; dst=w2ts;                C=2048; dstStride=4096; seS=2048L*2048; deS=2048;       BX=32; nPer=1024; }
  else                  { bid-=18432; src=rw2; dst=rw2t;                C=2048; dstStride=512;  seS=512L*2048;  deS=2048L*512;  BX=32; nPer=256; }
  const int e  = bid / nPer;
  const int rem = bid - e * nPer;
  const int by = rem / BX;
  const int bx = rem - by * BX;
  tcast_tile(src + (long)e * seS, dst + (long)e * deS, C, dstStride,
             bx * 64, by * 64, threadIdx.x);
}

// gate: sigmoid(x @ gate_w^T), top-6 -> (idx, normalized weight) per token
__global__ void gate_topk(const float* __restrict__ x, const float* __restrict__ gw,
                          int* __restrict__ tk_idx, float* __restrict__ tk_w,
                          float* __restrict__ aux) {
  int lane = threadIdx.x & 63;
  int wave = threadIdx.x >> 6;
  int token = blockIdx.x * 4 + wave;
  const float* xr = x + (long)token * HID;
  float xv[32];
#pragma unroll
  for (int i = 0; i < 32; ++i) xv[i] = xr[lane + i * 64];
  float sc[NEXP];
#pragma unroll
  for (int e = 0; e < NEXP; ++e) {
    const float* g = gw + (long)e * HID;
    float s = 0.f;
#pragma unroll
    for (int i = 0; i < 32; ++i) s += xv[i] * g[lane + i * 64];
#pragma unroll
    for (int off = 32; off > 0; off >>= 1) s += __shfl_down(s, off);
    sc[e] = s;
  }
  if (lane == 0) {
    float sg[NEXP];
#pragma unroll
    for (int e = 0; e < NEXP; ++e) sg[e] = 1.0f / (1.0f + expf(-sc[e]));
    unsigned taken = 0;
    int   sel[TOPK];
    float sw[TOPK];
    float sum = 0.f;
    for (int k = 0; k < TOPK; ++k) {
      float best = -1.f; int bi = 0;
#pragma unroll
      for (int e = 0; e < NEXP; ++e) {
        bool avail = !(taken & (1u << e));
        if (avail && sg[e] > best) { best = sg[e]; bi = e; }
      }
      taken |= (1u << bi);
      sel[k] = bi; sw[k] = best; sum += best;
    }
    float inv = 1.0f / (sum + 1e-9f);
#pragma unroll
    for (int k = 0; k < TOPK; ++k) {
      tk_idx[token * TOPK + k] = sel[k];
      tk_w[token * TOPK + k]   = sw[k] * inv;
    }
  }
  if (blockIdx.x == 0 && threadIdx.x == 0) *aux = 0.0f;
}

// dispatch: per-expert token lists + tile tables (256-row for up, 128 for down)
__global__ void dispatch(const int* __restrict__ tk_idx, const float* __restrict__ tk_w,
                         int* __restrict__ perm, float* __restrict__ wslot,
                         int* __restrict__ slot_of, int* __restrict__ meta,
                         int* __restrict__ uptab, int* __restrict__ dntab) {
  __shared__ int cnt[NEXP], cnt2[NEXP], off[NEXP + 1];
  int tid = threadIdx.x;
  if (tid < NEXP) { cnt[tid] = 0; cnt2[tid] = 0; }
  __syncthreads();
  for (int i = tid; i < NSLOT; i += 1024) atomicAdd(&cnt[tk_idx[i]], 1);
  __syncthreads();
  if (tid == 0) {
    int o = 0, un = 0, dn = 0;
    for (int e = 0; e < NEXP; ++e) {
      off[e] = o;
      int c = cnt[e];
      for (int r0 = 0; r0 < c; r0 += 256) uptab[un++] = (e << 16) | r0;
      for (int r0 = 0; r0 < c; r0 += 128) dntab[dn++] = (e << 16) | r0;
      o += c;
    }
    off[NEXP] = o;
    meta[0] = un; meta[1] = dn;
    for (int e = 0; e < NEXP; ++e) { meta[8 + e] = cnt[e]; meta[32 + e] = off[e]; }
  }
  __syncthreads();
  for (int i = tid; i < NSLOT; i += 1024) {
    int e = tk_idx[i];
    int loc = atomicAdd(&cnt2[e], 1);
    int slot = off[e] + loc;
    perm[slot] = i / TOPK;
    wslot[slot] = tk_w[i];
    slot_of[i] = slot;
  }
}

// ------- merged up GEMM: 256x128 dual-B, BK=64, 2-slot dbuf, 8-phase -------
// Half-tiles per K-tile: A0(rows0-127) A1(rows128-255) B1 B3, 16KB each,
// 2 global_load_lds/thread. Phase stages chosen so every current-slot write
// happens one barrier after that region's last ds_read (WAR-safe by barrier).
// Boundary vmcnt(6) leaves newest 3 half-tiles (t+2) in flight.
__global__ __launch_bounds__(512, 1) void gemm_up(
    const bf16_t* __restrict__ xb, const bf16_t* __restrict__ w1t,
    const bf16_t* __restrict__ w3t, bf16_t* __restrict__ hsh,
    bf16_t* __restrict__ hr, const int* __restrict__ perm,
    const float* __restrict__ wslot, const int* __restrict__ meta,
    const int* __restrict__ uptab) {
  __shared__ bf16_t lds[2 * 32768];   // slot: A0 8192 | A1 8192 | B1 8192 | B3 8192
  const int bid = blockIdx.x;
  const int tid  = threadIdx.x;
  const int lane = tid & 63;
  const int wave = tid >> 6;
  const int wm = wave >> 2;           // 0..1 -> 128-row half of the 256-row tile
  const int wc = wave & 3;            // 0..3 -> 32-col group
  const bool role_sh = bid < 512;
  int m0 = 0, j0 = 0, jc = 0, M = 256, bslot = 0;
  const bf16_t *b1G, *b3G;
  if (role_sh) {
    m0 = (bid >> 5) * 256; j0 = (bid & 31) * 128;
    b1G = w1t + (long)j0 * HID;
    b3G = w3t + (long)j0 * HID;
  } else {
    int t = bid - 512;
    int rt = t >> 2; jc = t & 3;
    if (rt >= meta[0]) return;
    int pk = uptab[rt];
    int e = pk >> 16, row0 = pk & 0xffff;
    bslot = meta[32 + e] + row0;
    M = min(256, meta[8 + e] - row0);
    int col = SHCOL + e * 512 + jc * 128;
    b1G = w1t + (long)col * HID;
    b3G = w3t + (long)col * HID;
  }
  // half-tile staging descriptors: h in {0:A0, 1:A1, 2:B1, 3:B3}, it in {0,1}
  const bf16_t* hsrc[4][2];
  int hloff[4][2];
#pragma unroll
  for (int it = 0; it < 2; ++it) {
    const int idx = it * 512 + tid;      // 0..1023 chunks of 16B
    const int r = idx >> 3;              // 0..127 row within half
    const int c = idx & 7;               // chunk within 128B row
    const int cs = c ^ (r & 7);          // pre-swizzled source chunk
    long rowA0, rowA1;
    if (role_sh) {
      rowA0 = (long)(m0 + r) * HID;
      rowA1 = (long)(m0 + 128 + r) * HID;
    } else {
      rowA0 = (long)perm[bslot + ((r < M) ? r : 0)] * HID;
      rowA1 = (long)perm[bslot + ((128 + r < M) ? 128 + r : 0)] * HID;
    }
    hsrc[0][it] = xb + rowA0 + cs * 8;          hloff[0][it] = idx * 8;
    hsrc[1][it] = xb + rowA1 + cs * 8;          hloff[1][it] = 8192 + idx * 8;
    hsrc[2][it] = b1G + (long)r * HID + cs * 8; hloff[2][it] = 16384 + idx * 8;
    hsrc[3][it] = b3G + (long)r * HID + cs * 8; hloff[3][it] = 24576 + idx * 8;
  }
  auto SH = [&](int t, int h) {          // stage half-tile h of K-tile t
    bf16_t* sb = lds + (t & 1) * 32768;
    async_copy16(hsrc[h][0] + t * 64, sb + hloff[h][0]);
    async_copy16(hsrc[h][1] + t * 64, sb + hloff[h][1]);
  };

  f32x4 acc1[8][2] = {};
  f32x4 acc3[8][2] = {};
  const int NT = HID / 64;              // 32 K-tiles
  const int lrow = lane & 15;
  const int lk   = lane >> 4;           // 8-elem group within 32-k MFMA span
  // prologue: tile0 all 4 halves; tile1 A0,A1,B1 (B3 comes at P0 of t=0)
  SH(0, 0); SH(0, 1); SH(0, 2); SH(0, 3);
  if (NT > 1) { SH(1, 0); SH(1, 1); SH(1, 2); }

  for (int t = 0; t < NT; ++t) {
    // boundary: prove K-tile t fully resident (all waves), keep 3 newest in flight
    if (t + 1 < NT) wait_vm<6>();
    else            wait_vm<0>();
    barp();
    const bf16_t* sb  = lds + (t & 1) * 32768;
    const bf16_t* aR  = sb + wm * 8192;        // this wave's A half-region
    const bf16_t* b1R = sb + 16384;
    const bf16_t* b3R = sb + 24576;
    bf16x8 a[4][2], b1f[2][2], b3f[2][2];
    // ---- P0: read aL + b1; stage (t+1, B3) [other slot]
#pragma unroll
    for (int fm = 0; fm < 4; ++fm)
#pragma unroll
      for (int kk = 0; kk < 2; ++kk)
        a[fm][kk] = frag64(aR, fm * 16 + lrow, kk * 4 + lk);
#pragma unroll
    for (int fn = 0; fn < 2; ++fn)
#pragma unroll
      for (int kk = 0; kk < 2; ++kk)
        b1f[fn][kk] = frag64(b1R, wc * 32 + fn * 16 + lrow, kk * 4 + lk);
    if (t + 1 < NT) SH(t + 1, 3);
    barp();
    __builtin_amdgcn_s_setprio(1);
#pragma unroll
    for (int kk = 0; kk < 2; ++kk)
#pragma unroll
      for (int fn = 0; fn < 2; ++fn)
#pragma unroll
        for (int fm = 0; fm < 4; ++fm)
          acc1[fm][fn] = __builtin_amdgcn_mfma_f32_16x16x32_bf16(a[fm][kk], b1f[fn][kk], acc1[fm][fn], 0, 0, 0);
    __builtin_amdgcn_s_setprio(0);
    barp();
    // ---- P1: read b3; stage (t+2, B1) [B1 reads retired in P0]
#pragma unroll
    for (int fn = 0; fn < 2; ++fn)
#pragma unroll
      for (int kk = 0; kk < 2; ++kk)
        b3f[fn][kk] = frag64(b3R, wc * 32 + fn * 16 + lrow, kk * 4 + lk);
    if (t + 2 < NT) SH(t + 2, 2);
    barp();
    __builtin_amdgcn_s_setprio(1);
#pragma unroll
    for (int kk = 0; kk < 2; ++kk)
#pragma unroll
      for (int fn = 0; fn < 2; ++fn)
#pragma unroll
        for (int fm = 0; fm < 4; ++fm)
          acc3[fm][fn] = __builtin_amdgcn_mfma_f32_16x16x32_bf16(a[fm][kk], b3f[fn][kk], acc3[fm][fn], 0, 0, 0);
    __builtin_amdgcn_s_setprio(0);
    barp();
    // ---- P2: read aH (overwrite a regs)
#pragma unroll
    for (int fm = 0; fm < 4; ++fm)
#pragma unroll
      for (int kk = 0; kk < 2; ++kk)
        a[fm][kk] = frag64(aR, 64 + fm * 16 + lrow, kk * 4 + lk);
    barp();
    __builtin_amdgcn_s_setprio(1);
#pragma unroll
    for (int kk = 0; kk < 2; ++kk)
#pragma unroll
      for (int fn = 0; fn < 2; ++fn)
#pragma unroll
        for (int fm = 0; fm < 4; ++fm)
          acc1[4 + fm][fn] = __builtin_amdgcn_mfma_f32_16x16x32_bf16(a[fm][kk], b1f[fn][kk], acc1[4 + fm][fn], 0, 0, 0);
    __builtin_amdgcn_s_setprio(0);
    barp();
    // ---- P3: stage (t+2, A0), (t+2, A1) [A reads retired by P2's wait]
    if (t + 2 < NT) { SH(t + 2, 0); SH(t + 2, 1); }
    barp();
    __builtin_amdgcn_s_setprio(1);
#pragma unroll
    for (int kk = 0; kk < 2; ++kk)
#pragma unroll
      for (int fn = 0; fn < 2; ++fn)
#pragma unroll
        for (int fm = 0; fm < 4; ++fm)
          acc3[4 + fm][fn] = __builtin_amdgcn_mfma_f32_16x16x32_bf16(a[fm][kk], b3f[fn][kk], acc3[4 + fm][fn], 0, 0, 0);
    __builtin_amdgcn_s_setprio(0);
    memfence_sched();
    // trailing barrier is next iteration's boundary barp()
  }
  const int mloc_base = wm * 128 + ((lane >> 4) << 2);
  const int cloc = wc * 32 + (lane & 15);
#pragma unroll
  for (int fm = 0; fm < 8; ++fm) {
#pragma unroll
    for (int jj = 0; jj < 4; ++jj) {
      const int mloc = mloc_base + fm * 16 + jj;
      if (role_sh) {
        bf16_t* dst = hsh + (long)(m0 + mloc) * SHCOL + j0 + cloc;
#pragma unroll
        for (int fn = 0; fn < 2; ++fn) {
          const float u1 = acc1[fm][fn][jj];
          const float u3 = acc3[fm][fn][jj];
          dst[fn * 16] = (bf16_t)((u1 / (1.0f + __expf(-u1))) * u3);
        }
      } else if (mloc < M) {
        const int slot = bslot + mloc;
        const float w = wslot[slot];
        bf16_t* dst = hr + (long)slot * 512 + jc * 128 + cloc;
#pragma unroll
        for (int fn = 0; fn < 2; ++fn) {
          const float u1 = acc1[fm][fn][jj];
          const float u3 = acc3[fm][fn][jj];
          dst[fn * 16] = (bf16_t)((u1 / (1.0f + __expf(-u1))) * u3 * w);
        }
      }
    }
  }
}

// ---------------- merged down GEMM (128x256, 3-slot ring, depth-2) --------
__global__ __launch_bounds__(512, 2) void gemm_down(
    const bf16_t* __restrict__ hsh, const bf16_t* __restrict__ w2ts,
    const bf16_t* __restrict__ hr, const bf16_t* __restrict__ rw2t,
    float* __restrict__ sout, bf16_t* __restrict__ y,
    const int* __restrict__ meta, const int* __restrict__ dntab) {
  __shared__ bf16_t lds[3 * 12288];   // slot: A 4096 | B 8192 elems
  const int bid = blockIdx.x;
  const int tid  = threadIdx.x;
  const int lane = tid & 63;
  const int wave = tid >> 6;
  const int wm = wave >> 2;
  const int wc = wave & 3;
  const bool role_sh = bid < 256;
  int m0 = 0, n0, M = 128, bslot = 0, NT;
  const bf16_t *aG, *bG;
  long lda, ldb;
  if (role_sh) {
    m0 = (bid >> 3) * 128; n0 = (bid & 7) * 256;
    aG = hsh + (long)m0 * SHCOL; lda = SHCOL;
    bG = w2ts + (long)n0 * SHCOL; ldb = SHCOL;
    NT = SHCOL / 32;                  // 128
  } else {
    int t = bid - 256;
    int rt = t >> 3; n0 = (t & 7) * 256;
    if (rt >= meta[1]) return;
    int pk = dntab[rt];
    int e = pk >> 16, row0 = pk & 0xffff;
    bslot = meta[32 + e] + row0;
    M = min(128, meta[8 + e] - row0);
    aG = hr + (long)bslot * 512; lda = 512;
    bG = rw2t + (long)e * (2048L * 512) + (long)n0 * 512; ldb = 512;
    NT = 512 / 32;                    // 16
  }
  const bf16_t* gsrc[3];
  int loff[3];
#pragma unroll
  for (int it = 0; it < 3; ++it) {
    int idx = it * 512 + tid;
    if (idx < 512) {                      // A: 128 rows x 4 chunks
      int r = idx >> 2, c = idx & 3;
      gsrc[it] = aG + (long)r * lda + ((c ^ ((r >> 1) & 3)) << 3);
      loff[it] = idx << 3;
    } else {                              // B: 256 rows x 4 chunks
      int i2 = idx - 512; int r = i2 >> 2, c = i2 & 3;
      gsrc[it] = bG + (long)r * ldb + ((c ^ ((r >> 1) & 3)) << 3);
      loff[it] = 4096 + (i2 << 3);
    }
  }
  auto STAGE = [&](int t) {
    bf16_t* sb = lds + (t % 3) * 12288;
#pragma unroll
    for (int it = 0; it < 3; ++it)
      async_copy16(gsrc[it] + t * 32, sb + loff[it]);
  };

  f32x4 acc[4][4] = {};
  const int rA = wm * 64 + (lane & 15);
  const int rB = wc * 64 + (lane & 15);
  const int cc = lane >> 4;
  STAGE(0); STAGE(1);
  for (int t = 0; t < NT; ++t) {
    if (t + 1 < NT) wait_vm<3>();     // drain S(t); S(t+1) stays in flight
    else            wait_vm<0>();
    __builtin_amdgcn_s_barrier();     // all waves done compute(t-1)
    memfence_sched();
    if (t + 2 < NT) STAGE(t + 2);     // slot (t+2)%3 = (t-1)%3, safe after bar
    const bf16_t* sb = lds + (t % 3) * 12288;
    bf16x8 a[4], b[4];
#pragma unroll
    for (int fm = 0; fm < 4; ++fm) a[fm] = frag32(sb, rA + fm * 16, cc);
#pragma unroll
    for (int fn = 0; fn < 4; ++fn) b[fn] = frag32(sb + 4096, rB + fn * 16, cc);
    __builtin_amdgcn_s_setprio(1);
#pragma unroll
    for (int fn = 0; fn < 4; ++fn)
#pragma unroll
      for (int fm = 0; fm < 4; ++fm)
        acc[fm][fn] = __builtin_amdgcn_mfma_f32_16x16x32_bf16(a[fm], b[fn], acc[fm][fn], 0, 0, 0);
    __builtin_amdgcn_s_setprio(0);
    memfence_sched();
  }
  const int mloc_base = wm * 64 + ((lane >> 4) << 2);
  const int cbase = n0 + wc * 64 + (lane & 15);
#pragma unroll
  for (int fm = 0; fm < 4; ++fm)
#pragma unroll
    for (int jj = 0; jj < 4; ++jj) {
      const int mloc = mloc_base + fm * 16 + jj;
      if (role_sh) {
#pragma unroll
        for (int fn = 0; fn < 4; ++fn)
          sout[(long)(m0 + mloc) * HID + cbase + fn * 16] = acc[fm][fn][jj];
      } else if (mloc < M) {
#pragma unroll
        for (int fn = 0; fn < 4; ++fn)
          y[(long)(bslot + mloc) * HID + cbase + fn * 16] = (bf16_t)acc[fm][fn][jj];
      }
    }
}

// combine: out[n] = s_out[n] + sum_k y[slot_of[n][k]]
__global__ void combine(const float* __restrict__ sout, const bf16_t* __restrict__ y,
                        const int* __restrict__ slot_of, float* __restrict__ out) {
  const int n = blockIdx.x;
  const int c0 = threadIdx.x * 8;
  float acc[8];
  const float4* sp = (const float4*)(sout + (long)n * HID + c0);
  float4 s0 = sp[0], s1 = sp[1];
  acc[0]=s0.x; acc[1]=s0.y; acc[2]=s0.z; acc[3]=s0.w;
  acc[4]=s1.x; acc[5]=s1.y; acc[6]=s1.z; acc[7]=s1.w;
#pragma unroll
  for (int k = 0; k < TOPK; ++k) {
    int slot = slot_of[n * TOPK + k];
    bf16x8 v = *(const bf16x8*)(y + (long)slot * HID + c0);
#pragma unroll
    for (int i = 0; i < 8; ++i) acc[i] += (float)v[i];
  }
  float4* op = (float4*)(out + (long)n * HID + c0);
  op[0] = make_float4(acc[0], acc[1], acc[2], acc[3]);
  op[1] = make_float4(acc[4], acc[5], acc[6], acc[7]);
}

__global__ void fill_sentinel(float* out, int n) {
  for (int i = blockIdx.x * 256 + threadIdx.x; i < n; i += gridDim.x * 256)
    out[i] = 12345.0f;
}

// ---------------- launch ----------------
extern "C" void kernel_launch(void* const* d_in, const int* in_sizes, int n_in,
                              void* d_out, int out_size, void* d_ws, size_t ws_size,
                              hipStream_t stream) {
  (void)in_sizes; (void)n_in;
  const float* x   = (const float*)d_in[0];
  const float* gw  = (const float*)d_in[1];
  const float* sw1 = (const float*)d_in[2];
  const float* sw2 = (const float*)d_in[3];   // dict order: w1, w2, w3
  const float* sw3 = (const float*)d_in[4];
  const float* rw1 = (const float*)d_in[5];
  const float* rw2 = (const float*)d_in[6];
  const float* rw3 = (const float*)d_in[7];
  float* out = (float*)d_out;

  const size_t OFF_XB    = 0;
  const size_t OFF_W1T   = 16777216;
  const size_t OFF_W3T   = 83886080;
  const size_t OFF_W2TS  = 150994944;
  const size_t OFF_RW2T  = 167772160;
  const size_t OFF_HSH   = 218103808;
  const size_t OFF_HR    = 251658240;
  const size_t OFF_SOUT  = 277086208;
  const size_t OFF_TKI   = 310640640;
  const size_t OFF_TKW   = 310738944;
  const size_t OFF_PERM  = 310837248;
  const size_t OFF_WSLOT = 310935552;
  const size_t OFF_SLOTOF= 311033856;
  const size_t OFF_META  = 311132160;
  const size_t OFF_UPTAB = 311136256;
  const size_t OFF_DNTAB = 311140352;
  const size_t NEED      = 311148544;
  if (ws_size < NEED) {
    fill_sentinel<<<4096, 256, 0, stream>>>(out, out_size);
    return;
  }
  char* ws = (char*)d_ws;
  bf16_t* xb     = (bf16_t*)(ws + OFF_XB);
  bf16_t* w1t    = (bf16_t*)(ws + OFF_W1T);
  bf16_t* w3t    = (bf16_t*)(ws + OFF_W3T);
  bf16_t* w2ts   = (bf16_t*)(ws + OFF_W2TS);
  bf16_t* rw2t   = (bf16_t*)(ws + OFF_RW2T);
  bf16_t* hsh    = (bf16_t*)(ws + OFF_HSH);
  bf16_t* hr     = (bf16_t*)(ws + OFF_HR);
  float*  sout   = (float*)(ws + OFF_SOUT);
  bf16_t* y      = (bf16_t*)(ws + OFF_W1T);   // overlay (dead after up GEMM)
  int*    tki    = (int*)(ws + OFF_TKI);
  float*  tkw    = (float*)(ws + OFF_TKW);
  int*    perm   = (int*)(ws + OFF_PERM);
  float*  wslot  = (float*)(ws + OFF_WSLOT);
  int*    slotof = (int*)(ws + OFF_SLOTOF);
  int*    meta   = (int*)(ws + OFF_META);
  int*    uptab  = (int*)(ws + OFF_UPTAB);
  int*    dntab  = (int*)(ws + OFF_DNTAB);

  gate_topk<<<1024, 256, 0, stream>>>(x, gw, tki, tkw, out + (size_t)NTOK * HID);
  dispatch<<<1, 1024, 0, stream>>>(tki, tkw, perm, wslot, slotof, meta, uptab, dntab);
  prep<<<32768, 256, 0, stream>>>(x, xb, sw1, rw1, sw3, rw3, sw2, rw2,
                                  w1t, w3t, w2ts, rw2t);

  gemm_up<<<dim3(512 + 480), 512, 0, stream>>>(xb, w1t, w3t, hsh, hr, perm, wslot, meta, uptab);
  gemm_down<<<dim3(256 + 1728), 512, 0, stream>>>(hsh, w2ts, hr, rw2t, sout, y, meta, dntab);
  combine<<<dim3(NTOK), 256, 0, stream>>>(sout, y, slotof, out);
}